// Round 4
// baseline (68.080 us; speedup 1.0000x reference)
//
#include <hip/hip_runtime.h>
#include <math.h>

#define FS 8
#define CC 3
#define HH 720
#define WW 1280
#define HW (HH * WW)

// 2D tiling: 64 wide x 8 tall per block, 2 pixels per thread (rows h, h+4)
#define TW 64
#define TH 8
#define GX (WW / TW)    // 20
#define GY (HH / TH)    // 90
#define NWG (GX * GY)   // 1800 (divisible by 8 -> clean XCD swizzle)

// fp16 workspace layout: copy A at even base, copy B at odd base (+1),
// so any 8-tap window is ONE 4B-aligned dwordx4.
#define SW 1288                 // fp16 row stride (even, >= 1280+8)
#define PLANE (HH * SW)
#define WS_HALFS (6 * PLANE + 8)
#define WS_BYTES ((size_t)WS_HALFS * 2)

typedef float f4 __attribute__((ext_vector_type(4), aligned(4)));
typedef _Float16 h8 __attribute__((ext_vector_type(8), aligned(4)));

// cos(pi*k/8), sin(pi*k/8), (-1)^k for k = -3..4 (index j = k+3)
__constant__ float COSK[8] = {0.38268343f, 0.70710678f, 0.92387953f, 1.0f,
                              0.92387953f, 0.70710678f, 0.38268343f, 0.0f};
__constant__ float SINK[8] = {-0.92387953f, -0.70710678f, -0.38268343f, 0.0f,
                              0.38268343f, 0.70710678f, 0.92387953f, 1.0f};
__constant__ float SGNK[8] = {-1.0f, 1.0f, -1.0f, 1.0f, -1.0f, 1.0f, -1.0f, 1.0f};

__device__ __forceinline__ void sinc_weights(float s, float* wgt) {
    const float PI = 3.14159265358979f;
    float sp = __sinf(PI * s);
    float s8, c8;
    __sincosf(PI * s * 0.125f, &s8, &c8);
#pragma unroll
    for (int j = 0; j < 8; ++j) {
        float t = s - (float)(j - 3);
        float win = c8 * COSK[j] + s8 * SINK[j];
        float r = (t == 0.0f) ? 1.0f : __fdividef(sp * SGNK[j], PI * t);
        wgt[j] = win * r;
    }
}

__device__ __forceinline__ float dot8(h8 v, const float* cx) {
    float r = (float)v[0] * cx[0];
    r = fmaf((float)v[1], cx[1], r);
    r = fmaf((float)v[2], cx[2], r);
    r = fmaf((float)v[3], cx[3], r);
    r = fmaf((float)v[4], cx[4], r);
    r = fmaf((float)v[5], cx[5], r);
    r = fmaf((float)v[6], cx[6], r);
    r = fmaf((float)v[7], cx[7], r);
    return r;
}

// x (f32 CHW) -> two fp16 copies in ws (even-base and odd-base)
__global__ __launch_bounds__(256) void conv_kernel(const float* __restrict__ x,
                                                   _Float16* __restrict__ ws) {
    int tid = blockIdx.x * blockDim.x + threadIdx.x;
    if (tid >= CC * HH * (WW / 4)) return;
    int k4 = tid % (WW / 4);
    int rest = tid / (WW / 4);
    int k = k4 * 4;
    f4 v = *(const f4*)(x + rest * WW + k);
    int dst = rest * SW + k;
    _Float16 a = (_Float16)v.x, b = (_Float16)v.y,
             c = (_Float16)v.z, d = (_Float16)v.w;
    typedef _Float16 h4 __attribute__((ext_vector_type(4), aligned(8)));
    *(h4*)(ws + dst) = (h4){a, b, c, d};
    _Float16* wb = ws + 3 * PLANE + 1 + dst;
    wb[0] = a; wb[1] = b; wb[2] = c; wb[3] = d;
}

// exact f32 scalar path for border pixels
__device__ __forceinline__ void pixel_slow(const float* __restrict__ x,
                                           int bx, const int* yoffW,
                                           const float* cxw, const float* cyw,
                                           float& r0, float& r1, float& r2) {
    int xcl[8];
#pragma unroll
    for (int j = 0; j < 8; ++j) {
        int xx = bx + (j - 3);
        xcl[j] = min(max(xx, 0), WW - 1);
    }
    r0 = 0.f; r1 = 0.f; r2 = 0.f;
#pragma unroll
    for (int i = 0; i < 8; ++i) {
        int o = yoffW[i];
        float cyi = cyw[i];
        const float* p0 = x + o;
        const float* p1 = p0 + HW;
        const float* p2 = p1 + HW;
        float rs0 = 0.f, rs1 = 0.f, rs2 = 0.f;
#pragma unroll
        for (int j = 0; j < 8; ++j) {
            float cj = cxw[j];
            rs0 = fmaf(p0[xcl[j]], cj, rs0);
            rs1 = fmaf(p1[xcl[j]], cj, rs1);
            rs2 = fmaf(p2[xcl[j]], cj, rs2);
        }
        r0 = fmaf(cyi, rs0, r0);
        r1 = fmaf(cyi, rs1, r1);
        r2 = fmaf(cyi, rs2, r2);
    }
}

__device__ __forceinline__ void pixel_fast(const _Float16* __restrict__ hx,
                                           int s, const int* yoffS,
                                           const float* cxw, const float* cyw,
                                           float& r0, float& r1, float& r2) {
    const _Float16* hp = hx + ((s & 1) ? (3 * PLANE + 1) : 0) + s;
    r0 = 0.f; r1 = 0.f; r2 = 0.f;
#pragma unroll
    for (int i = 0; i < 8; ++i) {
        int o = yoffS[i];
        float cyi = cyw[i];
        h8 v0 = *(const h8*)(hp + o);
        h8 v1 = *(const h8*)(hp + o + PLANE);
        h8 v2 = *(const h8*)(hp + o + 2 * PLANE);
        r0 = fmaf(cyi, dot8(v0, cxw), r0);
        r1 = fmaf(cyi, dot8(v1, cxw), r1);
        r2 = fmaf(cyi, dot8(v2, cxw), r2);
    }
}

__global__ __launch_bounds__(256) void warp_kernel(const float* __restrict__ x,
                                                   const float* __restrict__ flow,
                                                   const _Float16* __restrict__ hx,
                                                   float* __restrict__ out) {
    int bid = blockIdx.x;
    int swz = (bid & 7) * (NWG / 8) + (bid >> 3);
    int tx = swz % GX;
    int ty = swz / GX;
    int w = tx * TW + (threadIdx.x & 63);
    int hA = ty * TH + (threadIdx.x >> 6);      // rows hA and hA+4
    int hB = hA + 4;
    int idxA = hA * WW + w;
    int idxB = hB * WW + w;

    float fxA = flow[idxA], fyA = flow[HW + idxA];
    float fxB = flow[idxB], fyB = flow[HW + idxB];

    float rfxA = floorf(fxA), rfyA = floorf(fyA);
    float rfxB = floorf(fxB), rfyB = floorf(fyB);
    int bxA = w + (int)rfxA, byA = hA + (int)rfyA;
    int bxB = w + (int)rfxB, byB = hB + (int)rfyB;

    float cxwA[8], cywA[8], cxwB[8], cywB[8];
    sinc_weights(fxA - rfxA, cxwA);
    sinc_weights(fyA - rfyA, cywA);
    sinc_weights(fxB - rfxB, cxwB);
    sinc_weights(fyB - rfyB, cywB);

    // clipped row indices
    int yA[8], yB[8];
#pragma unroll
    for (int i = 0; i < 8; ++i) {
        yA[i] = min(max(byA + (i - 3), 0), HH - 1);
        yB[i] = min(max(byB + (i - 3), 0), HH - 1);
    }

    bool fastA = (bxA >= 3) && (bxA <= WW - 5);
    bool fastB = (bxB >= 3) && (bxB <= WW - 5);

    float a0, a1, a2, b0, b1, b2;

    if (fastA && fastB) {
        // interleaved dual-pixel fast path: 6 independent gathers in flight
        int sA = bxA - 3, sB = bxB - 3;
        const _Float16* hpA = hx + ((sA & 1) ? (3 * PLANE + 1) : 0) + sA;
        const _Float16* hpB = hx + ((sB & 1) ? (3 * PLANE + 1) : 0) + sB;
        a0 = a1 = a2 = b0 = b1 = b2 = 0.f;
#pragma unroll
        for (int i = 0; i < 8; ++i) {
            int oA = yA[i] * SW;
            int oB = yB[i] * SW;
            h8 va0 = *(const h8*)(hpA + oA);
            h8 va1 = *(const h8*)(hpA + oA + PLANE);
            h8 va2 = *(const h8*)(hpA + oA + 2 * PLANE);
            h8 vb0 = *(const h8*)(hpB + oB);
            h8 vb1 = *(const h8*)(hpB + oB + PLANE);
            h8 vb2 = *(const h8*)(hpB + oB + 2 * PLANE);
            float cA = cywA[i], cB = cywB[i];
            a0 = fmaf(cA, dot8(va0, cxwA), a0);
            a1 = fmaf(cA, dot8(va1, cxwA), a1);
            a2 = fmaf(cA, dot8(va2, cxwA), a2);
            b0 = fmaf(cB, dot8(vb0, cxwB), b0);
            b1 = fmaf(cB, dot8(vb1, cxwB), b1);
            b2 = fmaf(cB, dot8(vb2, cxwB), b2);
        }
    } else {
        // per-pixel dispatch (rare: near left/right borders)
        if (fastA) {
            int yS[8];
#pragma unroll
            for (int i = 0; i < 8; ++i) yS[i] = yA[i] * SW;
            pixel_fast(hx, bxA - 3, yS, cxwA, cywA, a0, a1, a2);
        } else {
            int yW[8];
#pragma unroll
            for (int i = 0; i < 8; ++i) yW[i] = yA[i] * WW;
            pixel_slow(x, bxA, yW, cxwA, cywA, a0, a1, a2);
        }
        if (fastB) {
            int yS[8];
#pragma unroll
            for (int i = 0; i < 8; ++i) yS[i] = yB[i] * SW;
            pixel_fast(hx, bxB - 3, yS, cxwB, cywB, b0, b1, b2);
        } else {
            int yW[8];
#pragma unroll
            for (int i = 0; i < 8; ++i) yW[i] = yB[i] * WW;
            pixel_slow(x, bxB, yW, cxwB, cywB, b0, b1, b2);
        }
    }

    out[idxA] = a0;
    out[HW + idxA] = a1;
    out[2 * HW + idxA] = a2;
    out[idxB] = b0;
    out[HW + idxB] = b1;
    out[2 * HW + idxB] = b2;
}

// fallback (f32 gathers only) if workspace is too small
__global__ __launch_bounds__(256) void warp_kernel_f32(const float* __restrict__ x,
                                                       const float* __restrict__ flow,
                                                       float* __restrict__ out) {
    int idx = blockIdx.x * blockDim.x + threadIdx.x;
    if (idx >= HW) return;
    int w = idx % WW;
    int h = idx / WW;
    float fx = flow[idx], fy = flow[HW + idx];
    float rfx = floorf(fx), rfy = floorf(fy);
    int bx = w + (int)rfx, by = h + (int)rfy;
    float cxw[8], cyw[8];
    sinc_weights(fx - rfx, cxw);
    sinc_weights(fy - rfy, cyw);
    int yW[8];
#pragma unroll
    for (int i = 0; i < 8; ++i) yW[i] = min(max(by + (i - 3), 0), HH - 1) * WW;
    float r0, r1, r2;
    pixel_slow(x, bx, yW, cxw, cyw, r0, r1, r2);
    out[idx] = r0;
    out[HW + idx] = r1;
    out[2 * HW + idx] = r2;
}

extern "C" void kernel_launch(void* const* d_in, const int* in_sizes, int n_in,
                              void* d_out, int out_size, void* d_ws, size_t ws_size,
                              hipStream_t stream) {
    const float* x = (const float*)d_in[0];
    const float* flow = (const float*)d_in[1];
    float* out = (float*)d_out;

    if (ws_size >= WS_BYTES) {
        _Float16* ws = (_Float16*)d_ws;
        int nconv = CC * HH * (WW / 4);
        conv_kernel<<<(nconv + 255) / 256, 256, 0, stream>>>(x, ws);
        warp_kernel<<<NWG, 256, 0, stream>>>(x, flow, ws, out);
    } else {
        warp_kernel_f32<<<(HW + 255) / 256, 256, 0, stream>>>(x, flow, out);
    }
}